// Round 8
// baseline (225.158 us; speedup 1.0000x reference)
//
#include <hip/hip_runtime.h>

#define N_CTX  256
#define T_LEN  1024
#define N_SEQ  4096
#define CHUNK  16
#define NCHUNK (T_LEN / CHUNK)          // 32
#define CTXCK  (N_CTX / CHUNK)          // 16 teacher-forced chunks

typedef float v2f __attribute__((ext_vector_type(2)));

__device__ __forceinline__ float fexp2(float x){ return __builtin_amdgcn_exp2f(x); }
__device__ __forceinline__ float frcp (float x){ return __builtin_amdgcn_rcpf(x); }
__device__ __forceinline__ v2f pk_fma(v2f a, v2f b, v2f c){ return __builtin_elementwise_fma(a, b, c); }

#define L1C 1.4426950408889634f   /* log2(e)   */
#define L2C 2.8853901631790583f   /* 2 log2(e) */
#define WCLAMP 100.0f             /* only the state-dependent exponent needs a clamp */

// Fast reciprocal: exponent bit-trick seed (~6% err) + 3 Newton steps
// (0.06 -> 3.6e-3 -> 1.3e-5 -> ~2e-10: exact to f32 rounding).
// Dependent latency ~28 cy on the FMA pipe vs ~75 cy for v_rcp_f32.
// Valid for finite x > 0 (our inputs are always > 1).
__device__ __forceinline__ float nrcp(float x){
    float y = __int_as_float(0x7EF311C3 - __float_as_int(x));
    y = y * fmaf(-x, y, 2.0f);
    y = y * fmaf(-x, y, 2.0f);
    y = y * fmaf(-x, y, 2.0f);
    return y;
}

// ---- packed 16-lane butterfly via DPP ----
template<int CTRL>
__device__ __forceinline__ v2f dpp_add2(v2f x){
    int y0 = __builtin_amdgcn_mov_dpp(__float_as_int(x.x), CTRL, 0xf, 0xf, true);
    int y1 = __builtin_amdgcn_mov_dpp(__float_as_int(x.y), CTRL, 0xf, 0xf, true);
    v2f y = { __int_as_float(y0), __int_as_float(y1) };
    return x + y;
}
__device__ __forceinline__ v2f red16_2(v2f x){
    x = dpp_add2<0xB1>(x);    // quad_perm xor1
    x = dpp_add2<0x4E>(x);    // quad_perm xor2
    x = dpp_add2<0x124>(x);   // row_ror:4
    x = dpp_add2<0x128>(x);   // row_ror:8 -> full 16-lane sum, broadcast
    return x;
}

struct LaneW {                         // gate weights prescaled: (i,f,o)*-L1C, g*+L2C
    v2f wi0_if, wi1_if, wi0_go, wi1_go;
    v2f wh0_if, wh1_if, wh0_go, wh1_go;
    v2f bs_if, bs_go;
    v2f whr;                           // (w_hr[0][j], w_hr[1][j]) unscaled
};

__device__ __forceinline__ void load_chunk(float4* b, const float4* __restrict__ up, int base){
#pragma unroll
    for (int i = 0; i < CHUNK; ++i) b[i] = up[base + i];   // 16 independent dwordx4
}

// ================= ESTIMATION: batched, data-parallel per chunk =================
// Issue-bound (round-7 measurement): keep 1-instr HW v_rcp here, not Newton.
__device__ __forceinline__ void est_chunk(const float4* raw, int baseT, const LaneW& L,
                                          float& c, v2f& rh,
                                          float2* __restrict__ op2, int j)
{
    float P[CHUNK], Q[CHUNK], EO[CHUNK];
    // ---- E1: independent gate transcendentals for all 16 steps ----
#pragma unroll
    for (int i = 0; i < CHUNK; ++i) {
        const float4 x = raw[i];
        v2f xx = {x.x, x.x}, xy = {x.y, x.y};
        v2f y0 = {x.z, x.z}, y1 = {x.w, x.w};
        v2f gif = pk_fma(y1, L.wh1_if, pk_fma(y0, L.wh0_if,
                  pk_fma(xy, L.wi1_if, pk_fma(xx, L.wi0_if, L.bs_if))));
        v2f ggo = pk_fma(y1, L.wh1_go, pk_fma(y0, L.wh0_go,
                  pk_fma(xy, L.wi1_go, pk_fma(xx, L.wi0_go, L.bs_go))));
        const float u  = fexp2(gif.x);             // e^-i
        const float ef = fexp2(gif.y);             // e^-f
        const float v  = fexp2(ggo.x);             // e^{2g}
        const float eo = fexp2(ggo.y);             // e^-o
        const float A  = (1.0f + u) * (v + 1.0f);
        const float B  = 1.0f + ef;
        const float r  = frcp(A * B);
        P[i]  = A * r;                             // = sigmoid(f)
        Q[i]  = (v - 1.0f) * B * r;                // = sigm(i)*tanh(g)
        EO[i] = 1.0f + eo;
    }
    // ---- E2: the only recurrence — a 16-long fma chain ----
    float CA[CHUNK];
#pragma unroll
    for (int i = 0; i < CHUNK; ++i) { c = fmaf(P[i], c, Q[i]); CA[i] = c; }
    // ---- E3: independent output tails for all 16 steps ----
    v2f cap = rh;
#pragma unroll
    for (int i = 0; i < CHUNK; ++i) {
        const float w = fexp2(fminf(L2C * CA[i], WCLAMP));
        const float s = (w - 1.0f) * frcp(EO[i] * (w + 1.0f));
        v2f ss = {s, s};
        v2f hv = red16_2(ss * L.whr);
        cap = (j == i) ? hv : cap;
        if (i == CHUNK - 1) rh = hv;               // compile-time branch
    }
    float2 o; o.x = cap.x; o.y = cap.y;
    op2[baseT + j] = o;
}

// ================= PREDICTION: serial chain (h-recurrence irreducible) =========
struct ChunkX {
    v2f xif[CHUNK];                    // prescaled bias + x-part, gates (i,f)
    v2f xgo[CHUNK];                    // prescaled bias + x-part, gates (g,o)
};

__device__ __forceinline__ void transform_chunk(ChunkX& X, const float4* raw, const LaneW& L){
#pragma unroll
    for (int i = 0; i < CHUNK; ++i) {
        const float4 x = raw[i];
        v2f xx = {x.x, x.x}, xy = {x.y, x.y};
        X.xif[i] = pk_fma(xy, L.wi1_if, pk_fma(xx, L.wi0_if, L.bs_if));
        X.xgo[i] = pk_fma(xy, L.wi1_go, pk_fma(xx, L.wi0_go, L.bs_go));
    }
}

// Chain: gates(8) -> exps(T1) -> A,B(16) -> nrcp(28) -> c(4) -> mul/min(8)
//        -> exp2(T3) -> w+-1(4) -> nrcp(28) -> s(4) -> mul po(4) -> bfly(32)
// sigma(o)*whr runs OFF-chain via HW v_rcp (latency hidden under the c-path).
__device__ __forceinline__ void pred_step(v2f xif, v2f xgo, const LaneW& L,
                                          float& c, v2f& rh)
{
    v2f hh0 = {rh.x, rh.x}, hh1 = {rh.y, rh.y};
    v2f gif = pk_fma(hh1, L.wh1_if, pk_fma(hh0, L.wh0_if, xif));  // (-L1C*i, -L1C*f)
    v2f ggo = pk_fma(hh1, L.wh1_go, pk_fma(hh0, L.wh0_go, xgo));  // ( L2C*g, -L1C*o)
    const float u  = fexp2(gif.x);
    const float ef = fexp2(gif.y);
    const float v  = fexp2(ggo.x);
    const float eo = fexp2(ggo.y);
    const float so = frcp(1.0f + eo);            // off-chain: HW rcp, hidden
    v2f po = (v2f){so, so} * L.whr;              // sigma(o) * w_hr, off-chain
    const float A  = (1.0f + u) * (v + 1.0f);
    const float B  = 1.0f + ef;
    const float r  = nrcp(A * B);                // on-chain: Newton, ~28 cy
    const float t  = (v - 1.0f) * B;
    c = fmaf(c, A, t) * r;
    const float w  = fexp2(fminf(L2C * c, WCLAMP));
    const float iw = nrcp(w + 1.0f);             // on-chain: Newton, ~28 cy
    const float s  = (w - 1.0f) * iw;            // tanh(c)
    v2f ss = {s, s};
    rh = red16_2(ss * po);
}

__device__ __forceinline__ void pred_chunk(const ChunkX& X, int baseT, const LaneW& L,
                                           float& c, v2f& rh,
                                           float2* __restrict__ op2, int j)
{
    v2f cap = rh;
#pragma unroll
    for (int i = 0; i < CHUNK; ++i) {
        pred_step(X.xif[i], X.xgo[i], L, c, rh);
        cap = (j == i) ? rh : cap;     // predicated capture, no branch
    }
    float2 o; o.x = cap.x; o.y = cap.y;
    op2[baseT + j] = o;
}

// 16 lanes per sequence (one per hidden unit); 4 sequences per wave; 1 wave/SIMD.
__global__ __launch_bounds__(256, 1) void openlstm_kernel(
    const float* __restrict__ u,     // (B, T, 4) = [x0 x1 y0 y1]
    const float* __restrict__ w_ih,  // (64, 2)
    const float* __restrict__ w_hh,  // (64, 2)
    const float* __restrict__ b_ih,  // (64)
    const float* __restrict__ b_hh,  // (64)
    const float* __restrict__ w_hr,  // (2, 16)
    float* __restrict__ out)         // (B, T, 2)
{
    const int tid = blockIdx.x * blockDim.x + threadIdx.x;
    const int seq = tid >> 4;
    const int j   = tid & 15;

    LaneW L;
    {   // gate rows {j, 16+j, 32+j, 48+j} = i, f, g, o ; prescale into exp2 domain
        const int ri = j, rf = 16 + j, rg = 32 + j, ro = 48 + j;
        const v2f sif = {-L1C, -L1C};
        const v2f sgo = { L2C, -L1C};
        L.wi0_if = sif * (v2f){w_ih[ri*2+0], w_ih[rf*2+0]};
        L.wi1_if = sif * (v2f){w_ih[ri*2+1], w_ih[rf*2+1]};
        L.wi0_go = sgo * (v2f){w_ih[rg*2+0], w_ih[ro*2+0]};
        L.wi1_go = sgo * (v2f){w_ih[rg*2+1], w_ih[ro*2+1]};
        L.wh0_if = sif * (v2f){w_hh[ri*2+0], w_hh[rf*2+0]};
        L.wh1_if = sif * (v2f){w_hh[ri*2+1], w_hh[rf*2+1]};
        L.wh0_go = sgo * (v2f){w_hh[rg*2+0], w_hh[ro*2+0]};
        L.wh1_go = sgo * (v2f){w_hh[rg*2+1], w_hh[ro*2+1]};
        L.bs_if  = sif * (v2f){b_ih[ri] + b_hh[ri], b_ih[rf] + b_hh[rf]};
        L.bs_go  = sgo * (v2f){b_ih[rg] + b_hh[rg], b_ih[ro] + b_hh[ro]};
        L.whr    = (v2f){w_hr[j], w_hr[16 + j]};
    }

    const float4* __restrict__ up = (const float4*)u + (size_t)seq * T_LEN;
    float2* __restrict__ op2 = (float2*)out + (size_t)seq * T_LEN;

    float c = 0.0f;
    v2f rh = {0.0f, 0.0f};
    float4 rawA[CHUNK], rawB[CHUNK];   // static ping-pong, never runtime-indexed

    load_chunk(rawA, up, 0);
    load_chunk(rawB, up, CHUNK);

    // ---- estimation: batched data-parallel chunks [0,16) ----
#pragma unroll 1
    for (int ck = 0; ck < CTXCK; ck += 2) {
        est_chunk(rawA, ck * CHUNK, L, c, rh, op2, j);
        load_chunk(rawA, up, (ck + 2) * CHUNK);              // max chunk 16
        est_chunk(rawB, (ck + 1) * CHUNK, L, c, rh, op2, j);
        load_chunk(rawB, up, (ck + 3) * CHUNK);              // max chunk 17
    }

    // ---- prediction: recurrent chunks [16,32) ----
#pragma unroll 1
    for (int ck = CTXCK; ck < NCHUNK; ck += 2) {
        const int lA = (ck + 2 < NCHUNK) ? (ck + 2) : (NCHUNK - 1);
        const int lB = (ck + 3 < NCHUNK) ? (ck + 3) : (NCHUNK - 1);
        {
            ChunkX XA;
            transform_chunk(XA, rawA, L);
            load_chunk(rawA, up, lA * CHUNK);
            pred_chunk(XA, ck * CHUNK, L, c, rh, op2, j);
        }
        {
            ChunkX XB;
            transform_chunk(XB, rawB, L);
            load_chunk(rawB, up, lB * CHUNK);
            pred_chunk(XB, (ck + 1) * CHUNK, L, c, rh, op2, j);
        }
    }
}

extern "C" void kernel_launch(void* const* d_in, const int* in_sizes, int n_in,
                              void* d_out, int out_size, void* d_ws, size_t ws_size,
                              hipStream_t stream) {
    const float* u    = (const float*)d_in[0];
    const float* w_ih = (const float*)d_in[1];
    const float* w_hh = (const float*)d_in[2];
    const float* b_ih = (const float*)d_in[3];
    const float* b_hh = (const float*)d_in[4];
    const float* w_hr = (const float*)d_in[5];
    float* out = (float*)d_out;

    const int threads = 256;                       // 16 sequences / block
    const int blocks  = (N_SEQ * 16) / threads;    // 256 blocks -> 1 per CU
    hipLaunchKernelGGL(openlstm_kernel, dim3(blocks), dim3(threads), 0, stream,
                       u, w_ih, w_hh, b_ih, b_hh, w_hr, out);
}

// Round 9
// 213.319 us; speedup vs baseline: 1.0555x; 1.0555x over previous
//
#include <hip/hip_runtime.h>

#define N_CTX  256
#define T_LEN  1024
#define N_SEQ  4096
#define CHUNK  16
#define NCHUNK (T_LEN / CHUNK)          // 32
#define CTXCK  (N_CTX / CHUNK)          // 16 teacher-forced chunks

typedef float v2f __attribute__((ext_vector_type(2)));

__device__ __forceinline__ float fexp2(float x){ return __builtin_amdgcn_exp2f(x); }
__device__ __forceinline__ float frcp (float x){ return __builtin_amdgcn_rcpf(x); }
__device__ __forceinline__ v2f pk_fma(v2f a, v2f b, v2f c){ return __builtin_elementwise_fma(a, b, c); }

#define L1C 1.4426950408889634f   /* log2(e)   */
#define L2C 2.8853901631790583f   /* 2 log2(e) */
#define WCLAMP 100.0f             /* only the state-dependent exponent needs a clamp */

// ---- packed 16-lane butterfly via DPP ----
template<int CTRL>
__device__ __forceinline__ v2f dpp_add2(v2f x){
    int y0 = __builtin_amdgcn_mov_dpp(__float_as_int(x.x), CTRL, 0xf, 0xf, true);
    int y1 = __builtin_amdgcn_mov_dpp(__float_as_int(x.y), CTRL, 0xf, 0xf, true);
    v2f y = { __int_as_float(y0), __int_as_float(y1) };
    return x + y;
}
__device__ __forceinline__ v2f red16_2(v2f x){
    x = dpp_add2<0xB1>(x);    // quad_perm xor1
    x = dpp_add2<0x4E>(x);    // quad_perm xor2
    x = dpp_add2<0x124>(x);   // row_ror:4
    x = dpp_add2<0x128>(x);   // row_ror:8 -> full 16-lane sum, broadcast
    return x;
}

struct LaneW {                         // gate weights prescaled: (i,f,o)*-L1C, g*+L2C
    v2f wi0_if, wi1_if, wi0_go, wi1_go;
    v2f wh0_if, wh1_if, wh0_go, wh1_go;
    v2f bs_if, bs_go;
    v2f whr;                           // (w_hr[0][j], w_hr[1][j]) unscaled
};

__device__ __forceinline__ void load_chunk(float4* b, const float4* __restrict__ up, int base){
#pragma unroll
    for (int i = 0; i < CHUNK; ++i) b[i] = up[base + i];   // 16 independent dwordx4
}

// Packed rational core shared by both phases:
//  t1 = {1+u, 1+ef}; t2 = {v+1, v-1}; {A,t} = t1*t2  (A=(1+u)(v+1), t=(v-1)(1+ef))
static __device__ __forceinline__ void gate_core(float u, float ef, float v,
                                                 float& A, float& B, float& t){
    v2f t1 = (v2f){u, ef} + (v2f){1.0f, 1.0f};       // pk_add
    v2f t2 = (v2f){v, v}  + (v2f){1.0f, -1.0f};      // pk_add
    v2f At = t1 * t2;                                // pk_mul -> {A, t}
    A = At.x; t = At.y; B = t1.y;
}

// ================= ESTIMATION: batched, data-parallel per chunk =================
// Issue-bound (round-7 measurement): minimize instruction count.
__device__ __forceinline__ void est_chunk(const float4* raw, int baseT, const LaneW& L,
                                          float& c, v2f& rh,
                                          float2* __restrict__ op2, int j)
{
    float P[CHUNK], Q[CHUNK], EO[CHUNK];
    // ---- E1: independent gate transcendentals for all 16 steps ----
#pragma unroll
    for (int i = 0; i < CHUNK; ++i) {
        const float4 x = raw[i];
        v2f xx = {x.x, x.x}, xy = {x.y, x.y};
        v2f y0 = {x.z, x.z}, y1 = {x.w, x.w};
        v2f gif = pk_fma(y1, L.wh1_if, pk_fma(y0, L.wh0_if,
                  pk_fma(xy, L.wi1_if, pk_fma(xx, L.wi0_if, L.bs_if))));
        v2f ggo = pk_fma(y1, L.wh1_go, pk_fma(y0, L.wh0_go,
                  pk_fma(xy, L.wi1_go, pk_fma(xx, L.wi0_go, L.bs_go))));
        const float u  = fexp2(gif.x);             // e^-i
        const float ef = fexp2(gif.y);             // e^-f
        const float v  = fexp2(ggo.x);             // e^{2g}
        const float eo = fexp2(ggo.y);             // e^-o
        float A, B, t;
        gate_core(u, ef, v, A, B, t);
        const float r  = frcp(A * B);
        P[i]  = A * r;                             // = sigmoid(f)
        Q[i]  = t * r;                             // = sigm(i)*tanh(g)
        EO[i] = 1.0f + eo;
    }
    // ---- E2: the only recurrence — a 16-long fma chain ----
    float CA[CHUNK];
#pragma unroll
    for (int i = 0; i < CHUNK; ++i) { c = fmaf(P[i], c, Q[i]); CA[i] = c; }
    // ---- E3: independent output tails for all 16 steps ----
    v2f cap = rh;
#pragma unroll
    for (int i = 0; i < CHUNK; ++i) {
        const float w  = fexp2(fminf(L2C * CA[i], WCLAMP));
        v2f wpm = (v2f){w, w} + (v2f){1.0f, -1.0f};          // {w+1, w-1}
        const float s  = wpm.y * frcp(EO[i] * wpm.x);        // sigm(o)*tanh(c)
        v2f ss = {s, s};
        v2f hv = red16_2(ss * L.whr);
        cap = (j == i) ? hv : cap;
        if (i == CHUNK - 1) rh = hv;               // compile-time branch
    }
    float2 o; o.x = cap.x; o.y = cap.y;
    op2[baseT + j] = o;
}

// ================= PREDICTION: serial chain (h-recurrence irreducible) =========
struct ChunkX {
    v2f xif[CHUNK];                    // prescaled bias + x-part, gates (i,f)
    v2f xgo[CHUNK];                    // prescaled bias + x-part, gates (g,o)
};

__device__ __forceinline__ void transform_chunk(ChunkX& X, const float4* raw, const LaneW& L){
#pragma unroll
    for (int i = 0; i < CHUNK; ++i) {
        const float4 x = raw[i];
        v2f xx = {x.x, x.x}, xy = {x.y, x.y};
        X.xif[i] = pk_fma(xy, L.wi1_if, pk_fma(xx, L.wi0_if, L.bs_if));
        X.xgo[i] = pk_fma(xy, L.wi1_go, pk_fma(xx, L.wi0_go, L.bs_go));
    }
}

// Chain: gates(pk_fma x2) -> exps(v,u,ef) -> pk_adds/pk_mul -> mul AB -> HW rcp
//        -> c -> exp2 -> pk w±1 -> HW rcp -> s -> pk_mul po -> butterfly.
// o-path (eo exp, sigma(o) rcp, po mul) is OFF-chain, hidden in c-path stalls.
__device__ __forceinline__ void pred_step(v2f xif, v2f xgo, const LaneW& L,
                                          float& c, v2f& rh)
{
    v2f hh0 = {rh.x, rh.x}, hh1 = {rh.y, rh.y};
    v2f ggo = pk_fma(hh1, L.wh1_go, pk_fma(hh0, L.wh0_go, xgo));  // ( L2C*g, -L1C*o)
    v2f gif = pk_fma(hh1, L.wh1_if, pk_fma(hh0, L.wh0_if, xif));  // (-L1C*i, -L1C*f)
    const float v  = fexp2(ggo.x);     // c-path exps first
    const float u  = fexp2(gif.x);
    const float ef = fexp2(gif.y);
    float A, B, t;
    gate_core(u, ef, v, A, B, t);
    const float r  = frcp(A * B);                  // on-chain HW rcp (~40 cy)
    const float eo = fexp2(ggo.y);                 // off-chain from here...
    const float so = frcp(1.0f + eo);
    v2f po = (v2f){so, so} * L.whr;                // sigma(o) * w_hr
    c = fmaf(c, A, t) * r;
    const float w  = fexp2(fminf(L2C * c, WCLAMP));
    v2f wpm = (v2f){w, w} + (v2f){1.0f, -1.0f};    // {w+1, w-1}
    const float s  = wpm.y * frcp(wpm.x);          // tanh(c)
    v2f ss = {s, s};
    rh = red16_2(ss * po);
}

__device__ __forceinline__ void pred_chunk(const ChunkX& X, int baseT, const LaneW& L,
                                           float& c, v2f& rh,
                                           float2* __restrict__ op2, int j)
{
    v2f cap = rh;
#pragma unroll
    for (int i = 0; i < CHUNK; ++i) {
        pred_step(X.xif[i], X.xgo[i], L, c, rh);
        cap = (j == i) ? rh : cap;     // predicated capture, no branch
    }
    float2 o; o.x = cap.x; o.y = cap.y;
    op2[baseT + j] = o;
}

// 16 lanes per sequence (one per hidden unit); 4 sequences per wave; 1 wave/SIMD.
__global__ __launch_bounds__(256, 1) void openlstm_kernel(
    const float* __restrict__ u,     // (B, T, 4) = [x0 x1 y0 y1]
    const float* __restrict__ w_ih,  // (64, 2)
    const float* __restrict__ w_hh,  // (64, 2)
    const float* __restrict__ b_ih,  // (64)
    const float* __restrict__ b_hh,  // (64)
    const float* __restrict__ w_hr,  // (2, 16)
    float* __restrict__ out)         // (B, T, 2)
{
    const int tid = blockIdx.x * blockDim.x + threadIdx.x;
    const int seq = tid >> 4;
    const int j   = tid & 15;

    LaneW L;
    {   // gate rows {j, 16+j, 32+j, 48+j} = i, f, g, o ; prescale into exp2 domain
        const int ri = j, rf = 16 + j, rg = 32 + j, ro = 48 + j;
        const v2f sif = {-L1C, -L1C};
        const v2f sgo = { L2C, -L1C};
        L.wi0_if = sif * (v2f){w_ih[ri*2+0], w_ih[rf*2+0]};
        L.wi1_if = sif * (v2f){w_ih[ri*2+1], w_ih[rf*2+1]};
        L.wi0_go = sgo * (v2f){w_ih[rg*2+0], w_ih[ro*2+0]};
        L.wi1_go = sgo * (v2f){w_ih[rg*2+1], w_ih[ro*2+1]};
        L.wh0_if = sif * (v2f){w_hh[ri*2+0], w_hh[rf*2+0]};
        L.wh1_if = sif * (v2f){w_hh[ri*2+1], w_hh[rf*2+1]};
        L.wh0_go = sgo * (v2f){w_hh[rg*2+0], w_hh[ro*2+0]};
        L.wh1_go = sgo * (v2f){w_hh[rg*2+1], w_hh[ro*2+1]};
        L.bs_if  = sif * (v2f){b_ih[ri] + b_hh[ri], b_ih[rf] + b_hh[rf]};
        L.bs_go  = sgo * (v2f){b_ih[rg] + b_hh[rg], b_ih[ro] + b_hh[ro]};
        L.whr    = (v2f){w_hr[j], w_hr[16 + j]};
    }

    const float4* __restrict__ up = (const float4*)u + (size_t)seq * T_LEN;
    float2* __restrict__ op2 = (float2*)out + (size_t)seq * T_LEN;

    float c = 0.0f;
    v2f rh = {0.0f, 0.0f};
    float4 rawA[CHUNK], rawB[CHUNK];   // static ping-pong, never runtime-indexed

    load_chunk(rawA, up, 0);
    load_chunk(rawB, up, CHUNK);

    // ---- estimation: batched data-parallel chunks [0,16) ----
#pragma unroll 1
    for (int ck = 0; ck < CTXCK; ck += 2) {
        est_chunk(rawA, ck * CHUNK, L, c, rh, op2, j);
        load_chunk(rawA, up, (ck + 2) * CHUNK);              // max chunk 16
        est_chunk(rawB, (ck + 1) * CHUNK, L, c, rh, op2, j);
        load_chunk(rawB, up, (ck + 3) * CHUNK);              // max chunk 17
    }

    // ---- prediction: recurrent chunks [16,32) ----
#pragma unroll 1
    for (int ck = CTXCK; ck < NCHUNK; ck += 2) {
        const int lA = (ck + 2 < NCHUNK) ? (ck + 2) : (NCHUNK - 1);
        const int lB = (ck + 3 < NCHUNK) ? (ck + 3) : (NCHUNK - 1);
        {
            ChunkX XA;
            transform_chunk(XA, rawA, L);
            load_chunk(rawA, up, lA * CHUNK);
            pred_chunk(XA, ck * CHUNK, L, c, rh, op2, j);
        }
        {
            ChunkX XB;
            transform_chunk(XB, rawB, L);
            load_chunk(rawB, up, lB * CHUNK);
            pred_chunk(XB, (ck + 1) * CHUNK, L, c, rh, op2, j);
        }
    }
}

extern "C" void kernel_launch(void* const* d_in, const int* in_sizes, int n_in,
                              void* d_out, int out_size, void* d_ws, size_t ws_size,
                              hipStream_t stream) {
    const float* u    = (const float*)d_in[0];
    const float* w_ih = (const float*)d_in[1];
    const float* w_hh = (const float*)d_in[2];
    const float* b_ih = (const float*)d_in[3];
    const float* b_hh = (const float*)d_in[4];
    const float* w_hr = (const float*)d_in[5];
    float* out = (float*)d_out;

    const int threads = 256;                       // 16 sequences / block
    const int blocks  = (N_SEQ * 16) / threads;    // 256 blocks -> 1 per CU
    hipLaunchKernelGGL(openlstm_kernel, dim3(blocks), dim3(threads), 0, stream,
                       u, w_ih, w_hh, b_ih, b_hh, w_hr, out);
}